// Round 1
// baseline (154.382 us; speedup 1.0000x reference)
//
#include <hip/hip_runtime.h>

#define SDIM 32    // state dim = 2*J
#define HDIM 34    // hidden
#define HP   36    // padded hidden (16B-aligned float4 rows: 36*4 = 144 = 9*16)
#define NEXP 12    // num experts
#define ACOL 256   // action dim = J*J
#define SPB  256   // states per block

__global__ __launch_bounds__(256) void actor_kernel(
    const float* __restrict__ states,
    const int*   __restrict__ epoch_idx,
    const float* __restrict__ W1,
    const float* __restrict__ b1,
    const float* __restrict__ Wout,
    const float* __restrict__ bout,
    const int*   __restrict__ mask,
    float*       __restrict__ out,
    int nB)
{
    __shared__ float w1s[HDIM * SDIM];      // 4.25 KB
    __shared__ float b1s[HDIM];
    __shared__ float xs[SPB][HP];           // 36 KB
    __shared__ int   cnt[NEXP];
    __shared__ int   off[NEXP];
    __shared__ unsigned short ord[SPB];     // slot ids grouped by expert

    const int t  = threadIdx.x;
    const int s0 = blockIdx.x * SPB;

    // stage W1, b1; zero counters
    for (int i = t; i < HDIM * SDIM; i += 256) w1s[i] = W1[i];
    if (t < HDIM) b1s[t] = b1[t];
    if (t < NEXP) cnt[t] = 0;
    __syncthreads();

    // ---- Phase 1: trunk. thread t <-> state s0+t ----
    const int  sidx  = s0 + t;
    const bool valid = (sidx < nB);
    int e = 0, rank = 0;
    if (valid) {
        float sr[SDIM];
        const float4* sp = (const float4*)(states + (size_t)sidx * SDIM);
        #pragma unroll
        for (int q = 0; q < SDIM / 4; ++q) {
            float4 v = sp[q];
            sr[4*q+0] = v.x; sr[4*q+1] = v.y; sr[4*q+2] = v.z; sr[4*q+3] = v.w;
        }
        #pragma unroll 2
        for (int h = 0; h < HDIM; ++h) {
            float acc = b1s[h];
            const float4* wr = (const float4*)(w1s + h * SDIM);
            #pragma unroll
            for (int q = 0; q < SDIM / 4; ++q) {
                float4 wv = wr[q];
                acc = fmaf(sr[4*q+0], wv.x, acc);
                acc = fmaf(sr[4*q+1], wv.y, acc);
                acc = fmaf(sr[4*q+2], wv.z, acc);
                acc = fmaf(sr[4*q+3], wv.w, acc);
            }
            xs[t][h] = fmaxf(acc, 0.0f);
        }
        xs[t][HDIM]   = 0.0f;   // zero pad so 9th float4 contributes 0
        xs[t][HDIM+1] = 0.0f;
        e = epoch_idx[sidx];
        rank = atomicAdd(&cnt[e], 1);
    }
    __syncthreads();

    // ---- Phase 2: bucket offsets (counting sort by expert) ----
    if (t == 0) {
        int a = 0;
        #pragma unroll
        for (int i = 0; i < NEXP; ++i) { off[i] = a; a += cnt[i]; }
    }
    __syncthreads();
    if (valid) ord[off[e] + rank] = (unsigned short)t;
    __syncthreads();

    // ---- Phase 3: expert GEMV. thread t <-> output column t ----
    const bool  act = (mask[t] != 0);     // mask flat [16*16] == column index
    const float neg = -1e9f;

    for (int e2 = 0; e2 < NEXP; ++e2) {
        const int n = cnt[e2];
        if (n == 0) continue;

        // hold this expert's column weights in registers
        float w[HP];
        const float2* wp = (const float2*)(Wout + ((size_t)e2 * ACOL + t) * HDIM);
        #pragma unroll
        for (int q = 0; q < HDIM / 2; ++q) {
            float2 v = wp[q];
            w[2*q] = v.x; w[2*q+1] = v.y;
        }
        w[HDIM] = 0.0f; w[HDIM+1] = 0.0f;
        const float bb  = bout[e2 * ACOL + t];
        const int  base = off[e2];

        int slot = ord[base];             // prefetch first slot
        for (int j = 0; j < n; ++j) {
            const int nslot = (j + 1 < n) ? (int)ord[base + j + 1] : 0;
            float acc0 = bb, acc1 = 0.0f;
            #pragma unroll
            for (int q = 0; q < HP / 4; q += 2) {
                const float4 xv = *(const float4*)&xs[slot][4*q];
                acc0 = fmaf(xv.x, w[4*q+0], acc0);
                acc0 = fmaf(xv.y, w[4*q+1], acc0);
                acc0 = fmaf(xv.z, w[4*q+2], acc0);
                acc0 = fmaf(xv.w, w[4*q+3], acc0);
            }
            #pragma unroll
            for (int q = 1; q < HP / 4; q += 2) {
                const float4 xv = *(const float4*)&xs[slot][4*q];
                acc1 = fmaf(xv.x, w[4*q+0], acc1);
                acc1 = fmaf(xv.y, w[4*q+1], acc1);
                acc1 = fmaf(xv.z, w[4*q+2], acc1);
                acc1 = fmaf(xv.w, w[4*q+3], acc1);
            }
            out[(size_t)(s0 + slot) * ACOL + t] = act ? (acc0 + acc1) : neg;
            slot = nslot;
        }
    }
}

extern "C" void kernel_launch(void* const* d_in, const int* in_sizes, int n_in,
                              void* d_out, int out_size, void* d_ws, size_t ws_size,
                              hipStream_t stream) {
    const float* states    = (const float*)d_in[0];
    const int*   epoch_idx = (const int*)  d_in[1];
    const float* W1        = (const float*)d_in[2];
    const float* b1        = (const float*)d_in[3];
    const float* Wout      = (const float*)d_in[4];
    const float* bout      = (const float*)d_in[5];
    const int*   mask      = (const int*)  d_in[6];
    float*       out       = (float*)d_out;

    const int nB   = in_sizes[0] / SDIM;
    const int grid = (nB + SPB - 1) / SPB;
    actor_kernel<<<grid, 256, 0, stream>>>(states, epoch_idx, W1, b1,
                                           Wout, bout, mask, out, nB);
}

// Round 2
// 116.846 us; speedup vs baseline: 1.3212x; 1.3212x over previous
//
#include <hip/hip_runtime.h>

typedef __attribute__((ext_vector_type(8))) short short8;   // 8 bf16 = 4 VGPR (MFMA A/B frag)
typedef __attribute__((ext_vector_type(4))) float f32x4;    // MFMA C/D frag

#define SDIM 32
#define HDIM 34
#define NEXP 12
#define ACOL 256
#define SPB  256
#define MAXROWS 448   // 256 + 12*15 = 436 padded rows max, rounded up

// fp32 -> bf16 (round-to-nearest-ish), pack two into one dword
__device__ __forceinline__ unsigned int bpack(float lo, float hi) {
    unsigned int a = __builtin_bit_cast(unsigned int, lo);
    unsigned int b = __builtin_bit_cast(unsigned int, hi);
    return ((a + 0x8000u) >> 16) | ((b + 0x8000u) & 0xffff0000u);
}

__global__ __launch_bounds__(256) void actor_kernel(
    const float* __restrict__ states,
    const int*   __restrict__ epoch_idx,
    const float* __restrict__ W1,
    const float* __restrict__ b1,
    const float* __restrict__ Wout,
    const float* __restrict__ bout,
    const int*   __restrict__ mask,
    float*       __restrict__ out,
    int nB)
{
    // xs: bf16 rows, 64 k-slots (k0..33 real, rest zero), 128 B/row, XOR-swizzled
    __shared__ unsigned int xs[MAXROWS * 32];   // 57344 B
    __shared__ int   rowid[MAXROWS];            // block-local state id or -1
    __shared__ float w1s[HDIM * SDIM];
    __shared__ float b1s[HDIM];
    __shared__ int   cnt[NEXP];
    __shared__ int   goff[NEXP];                // padded row base per expert
    __shared__ int   ntl[NEXP];                 // 16-row tiles per expert

    const int t  = threadIdx.x;
    const int s0 = blockIdx.x * SPB;

    // ---- phase 0: stage W1/b1, zero xs, sentinel rowid, count experts ----
    for (int i = t; i < HDIM * SDIM; i += 256) w1s[i] = W1[i];
    if (t < HDIM) b1s[t] = b1[t];
    if (t < NEXP) cnt[t] = 0;
    {
        f32x4 z = {0.f, 0.f, 0.f, 0.f};
        f32x4* xz = (f32x4*)xs;
        for (int i = t; i < MAXROWS * 8; i += 256) xz[i] = z;
        for (int i = t; i < MAXROWS; i += 256) rowid[i] = -1;
    }
    const int  sidx  = s0 + t;
    const bool valid = (sidx < nB);
    int e = 0, rank = 0;
    float sr[SDIM];
    if (valid) {
        const float4* sp = (const float4*)(states + (size_t)sidx * SDIM);
        #pragma unroll
        for (int q = 0; q < SDIM / 4; ++q) {
            float4 v = sp[q];
            sr[4*q+0] = v.x; sr[4*q+1] = v.y; sr[4*q+2] = v.z; sr[4*q+3] = v.w;
        }
        e = epoch_idx[sidx];
        rank = atomicAdd(&cnt[e], 1);
    }
    __syncthreads();

    // ---- scan (t0) + trunk compute (all threads, overlapped) ----
    if (t == 0) {
        int base = 0;
        #pragma unroll
        for (int i = 0; i < NEXP; ++i) {
            goff[i] = base;
            int nt = (cnt[i] + 15) >> 4;
            ntl[i] = nt;
            base += nt << 4;
        }
    }
    float x[HDIM];
    if (valid) {
        #pragma unroll 2
        for (int h = 0; h < HDIM; ++h) {
            float acc = b1s[h];
            const float4* wr = (const float4*)(w1s + h * SDIM);
            #pragma unroll
            for (int q = 0; q < SDIM / 4; ++q) {
                float4 wv = wr[q];
                acc = fmaf(sr[4*q+0], wv.x, acc);
                acc = fmaf(sr[4*q+1], wv.y, acc);
                acc = fmaf(sr[4*q+2], wv.z, acc);
                acc = fmaf(sr[4*q+3], wv.w, acc);
            }
            x[h] = fmaxf(acc, 0.0f);
        }
    }
    __syncthreads();

    // ---- write bf16 x row into sorted+padded slot (swizzled) ----
    if (valid) {
        const int slot = goff[e] + rank;
        const unsigned int swz = (unsigned int)((slot & 7) << 4);
        char* rbase = (char*)xs + slot * 128;
        unsigned int d[17];
        #pragma unroll
        for (int k = 0; k < 17; ++k) d[k] = bpack(x[2*k], x[2*k+1]);
        #pragma unroll
        for (int c = 0; c < 4; ++c) {
            f32x4 q;
            q[0] = __builtin_bit_cast(float, d[4*c+0]);
            q[1] = __builtin_bit_cast(float, d[4*c+1]);
            q[2] = __builtin_bit_cast(float, d[4*c+2]);
            q[3] = __builtin_bit_cast(float, d[4*c+3]);
            *(f32x4*)(rbase + ((unsigned)(c * 16) ^ swz)) = q;
        }
        *(unsigned int*)(rbase + (64u ^ swz)) = d[16];   // k32,33
        rowid[slot] = t;
    }
    __syncthreads();

    // ---- phase 3: MFMA expert GEMM. wave w owns col-tiles 4w..4w+3 ----
    const int wv   = t >> 6;
    const int lane = t & 63;
    const int r    = lane & 15;     // A row / C col / B col within tile
    const int g    = lane >> 4;     // k-group
    const int colbase = wv * 64 + r;
    const float NEG = -1e9f;

    bool mk[4];
    #pragma unroll
    for (int j = 0; j < 4; ++j) mk[j] = (mask[colbase + j * 16] != 0);

    float* outb = out + (size_t)s0 * ACOL;

    for (int e2 = 0; e2 < NEXP; ++e2) {
        const int nt = ntl[e2];
        if (nt == 0) continue;

        // B-fragments for this expert: 4 col-tiles x 2 k-halves, in registers
        short8 bf1[4], bf2[4];
        float  bias[4];
        #pragma unroll
        for (int j = 0; j < 4; ++j) {
            const int col = colbase + j * 16;
            const float* wr = Wout + ((size_t)e2 * ACOL + col) * HDIM;
            const float2* wp = (const float2*)(wr + g * 8);   // 8B aligned
            float2 p0 = wp[0], p1 = wp[1], p2 = wp[2], p3 = wp[3];
            uint4 q1 = make_uint4(bpack(p0.x, p0.y), bpack(p1.x, p1.y),
                                  bpack(p2.x, p2.y), bpack(p3.x, p3.y));
            bf1[j] = __builtin_bit_cast(short8, q1);
            uint4 q2 = make_uint4(0u, 0u, 0u, 0u);
            if (g == 0) q2.x = bpack(wr[32], wr[33]);         // k=32,33; rest zero
            bf2[j] = __builtin_bit_cast(short8, q2);
            bias[j] = bout[e2 * ACOL + col];
        }

        const int tb = goff[e2];
        for (int st = 0; st < nt; ++st) {
            const int rb  = tb + (st << 4);
            const int row = rb + r;
            const unsigned int swz = (unsigned int)((row & 7) << 4);
            const char* rp = (const char*)xs + row * 128;
            short8 a1 = *(const short8*)(rp + ((unsigned)(g * 16) ^ swz));
            short8 a2 = *(const short8*)(rp + ((unsigned)(64 + g * 16) ^ swz));
            int4 rid = *(const int4*)(rowid + rb + g * 4);    // rows g*4..g*4+3

            #pragma unroll
            for (int j = 0; j < 4; ++j) {
                f32x4 acc = {bias[j], bias[j], bias[j], bias[j]};
                acc = __builtin_amdgcn_mfma_f32_16x16x32_bf16(a1, bf1[j], acc, 0, 0, 0);
                acc = __builtin_amdgcn_mfma_f32_16x16x32_bf16(a2, bf2[j], acc, 0, 0, 0);
                float* ob = outb + colbase + j * 16;
                if (rid.x >= 0) __builtin_nontemporal_store(mk[j] ? acc[0] : NEG, ob + (size_t)rid.x * ACOL);
                if (rid.y >= 0) __builtin_nontemporal_store(mk[j] ? acc[1] : NEG, ob + (size_t)rid.y * ACOL);
                if (rid.z >= 0) __builtin_nontemporal_store(mk[j] ? acc[2] : NEG, ob + (size_t)rid.z * ACOL);
                if (rid.w >= 0) __builtin_nontemporal_store(mk[j] ? acc[3] : NEG, ob + (size_t)rid.w * ACOL);
            }
        }
    }
}

extern "C" void kernel_launch(void* const* d_in, const int* in_sizes, int n_in,
                              void* d_out, int out_size, void* d_ws, size_t ws_size,
                              hipStream_t stream) {
    const float* states    = (const float*)d_in[0];
    const int*   epoch_idx = (const int*)  d_in[1];
    const float* W1        = (const float*)d_in[2];
    const float* b1        = (const float*)d_in[3];
    const float* Wout      = (const float*)d_in[4];
    const float* bout      = (const float*)d_in[5];
    const int*   mask      = (const int*)  d_in[6];
    float*       out       = (float*)d_out;

    const int nB   = in_sizes[0] / SDIM;
    const int grid = (nB + SPB - 1) / SPB;
    actor_kernel<<<grid, 256, 0, stream>>>(states, epoch_idx, W1, b1,
                                           Wout, bout, mask, out, nB);
}

// Round 4
// 98.357 us; speedup vs baseline: 1.5696x; 1.1880x over previous
//
#include <hip/hip_runtime.h>

typedef __attribute__((ext_vector_type(8))) short short8;   // 8 bf16 = 4 VGPR (MFMA A/B frag)
typedef __attribute__((ext_vector_type(4))) float f32x4;    // MFMA C/D frag
typedef __attribute__((ext_vector_type(4))) int   i32x4;

#define SDIM 32
#define HDIM 34
#define NEXP 12
#define ACOL 256
#define SPB  256
#define MAXROWS 432        // sum of per-expert 16-padded counts <= 432
#define STG_STRIDE 260     // 16-row f32 staging, +4 pad: 2-way LDS conflicts only

// fp32 -> bf16 (round-to-nearest-ish), pack two into one dword
__device__ __forceinline__ unsigned int bpack(float lo, float hi) {
    unsigned int a = __builtin_bit_cast(unsigned int, lo);
    unsigned int b = __builtin_bit_cast(unsigned int, hi);
    return ((a + 0x8000u) >> 16) | ((b + 0x8000u) & 0xffff0000u);
}

__global__ __launch_bounds__(256) void actor_kernel(
    const float* __restrict__ states,
    const int*   __restrict__ epoch_idx,
    const float* __restrict__ W1,
    const float* __restrict__ b1,
    const float* __restrict__ Wout,
    const float* __restrict__ bout,
    const int*   __restrict__ mask,
    float*       __restrict__ out,
    int nB)
{
    // xs: bf16 rows, 64 k-slots (k0..33 real, rest zero), 128 B/row, XOR-swizzled
    __shared__ unsigned int xs[MAXROWS * 32];       // 55296 B
    __shared__ float stg[16 * STG_STRIDE];          // 16640 B output tile staging
    __shared__ unsigned short rowid[MAXROWS];       // 864 B
    __shared__ float w1s[HDIM * SDIM];              // 4352 B
    __shared__ float b1s[HDIM];
    __shared__ int   cnt[NEXP];
    __shared__ int   goff[NEXP];
    __shared__ int   ntl[NEXP];

    const int t  = threadIdx.x;
    const int s0 = blockIdx.x * SPB;

    // ---- phase 0: stage W1/b1, zero xs, sentinel rowid, count experts ----
    for (int i = t; i < HDIM * SDIM; i += 256) w1s[i] = W1[i];
    if (t < HDIM) b1s[t] = b1[t];
    if (t < NEXP) cnt[t] = 0;
    {
        f32x4 z = {0.f, 0.f, 0.f, 0.f};
        f32x4* xz = (f32x4*)xs;
        for (int i = t; i < MAXROWS * 8; i += 256) xz[i] = z;
        for (int i = t; i < MAXROWS; i += 256) rowid[i] = 0xFFFFu;
    }
    const int  sidx  = s0 + t;
    const bool valid = (sidx < nB);
    int e = 0, rank = 0;
    float sr[SDIM];
    if (valid) {
        const float4* sp = (const float4*)(states + (size_t)sidx * SDIM);
        #pragma unroll
        for (int q = 0; q < SDIM / 4; ++q) {
            float4 v = sp[q];
            sr[4*q+0] = v.x; sr[4*q+1] = v.y; sr[4*q+2] = v.z; sr[4*q+3] = v.w;
        }
        e = epoch_idx[sidx];
        rank = atomicAdd(&cnt[e], 1);
    }
    __syncthreads();

    // ---- scan (t0) + trunk compute (all threads, overlapped) ----
    if (t == 0) {
        int base = 0;
        #pragma unroll
        for (int i = 0; i < NEXP; ++i) {
            goff[i] = base;
            int nt = (cnt[i] + 15) >> 4;
            ntl[i] = nt;
            base += nt << 4;
        }
    }
    float x[HDIM];
    if (valid) {
        #pragma unroll 2
        for (int h = 0; h < HDIM; ++h) {
            float acc = b1s[h];
            const float4* wr = (const float4*)(w1s + h * SDIM);
            #pragma unroll
            for (int q = 0; q < SDIM / 4; ++q) {
                float4 wv = wr[q];
                acc = fmaf(sr[4*q+0], wv.x, acc);
                acc = fmaf(sr[4*q+1], wv.y, acc);
                acc = fmaf(sr[4*q+2], wv.z, acc);
                acc = fmaf(sr[4*q+3], wv.w, acc);
            }
            x[h] = fmaxf(acc, 0.0f);
        }
    }
    __syncthreads();

    // ---- write bf16 x row into sorted+padded slot (swizzled) ----
    if (valid) {
        const int slot = goff[e] + rank;
        const unsigned int swz = (unsigned int)((slot & 7) << 4);
        char* rbase = (char*)xs + slot * 128;
        unsigned int d[17];
        #pragma unroll
        for (int k = 0; k < 17; ++k) d[k] = bpack(x[2*k], x[2*k+1]);
        #pragma unroll
        for (int c = 0; c < 4; ++c) {
            f32x4 q;
            q[0] = __builtin_bit_cast(float, d[4*c+0]);
            q[1] = __builtin_bit_cast(float, d[4*c+1]);
            q[2] = __builtin_bit_cast(float, d[4*c+2]);
            q[3] = __builtin_bit_cast(float, d[4*c+3]);
            *(f32x4*)(rbase + ((unsigned)(c * 16) ^ swz)) = q;
        }
        *(unsigned int*)(rbase + (64u ^ swz)) = d[16];   // k32,33
        rowid[slot] = (unsigned short)t;
    }
    __syncthreads();

    // ---- phase 3: MFMA expert GEMM; LDS-transposed coalesced row stores ----
    const int wv   = t >> 6;
    const int lane = t & 63;
    const int r    = lane & 15;     // A row / B col within tile
    const int g    = lane >> 4;     // k-group
    const int colbase = wv * 64 + r;
    const float NEG = -1e9f;
    const i32x4 mq = *(const i32x4*)(mask + 4 * lane);   // mask for cols 4*lane..+3

    float* outb = out + (size_t)s0 * ACOL;

    for (int e2 = 0; e2 < NEXP; ++e2) {
        const int nt = ntl[e2];
        if (nt == 0) continue;

        // B-fragments for this expert: 4 col-tiles x 2 k-halves, in registers
        short8 bf1[4], bf2[4];
        float  bias[4];
        #pragma unroll
        for (int j = 0; j < 4; ++j) {
            const int col = colbase + j * 16;
            const float* wr = Wout + ((size_t)e2 * ACOL + col) * HDIM;
            const float2* wp = (const float2*)(wr + g * 8);   // 8B aligned
            float2 p0 = wp[0], p1 = wp[1], p2 = wp[2], p3 = wp[3];
            uint4 q1 = make_uint4(bpack(p0.x, p0.y), bpack(p1.x, p1.y),
                                  bpack(p2.x, p2.y), bpack(p3.x, p3.y));
            bf1[j] = __builtin_bit_cast(short8, q1);
            uint4 q2 = make_uint4(0u, 0u, 0u, 0u);
            if (g == 0) q2.x = bpack(wr[32], wr[33]);         // k=32,33; rest zero
            bf2[j] = __builtin_bit_cast(short8, q2);
            bias[j] = bout[e2 * ACOL + col];
        }

        const int tb = goff[e2];
        for (int st = 0; st < nt; ++st) {
            const int rb  = tb + (st << 4);
            const int row = rb + r;
            const unsigned int swz = (unsigned int)((row & 7) << 4);
            const char* rp = (const char*)xs + row * 128;
            short8 a1 = *(const short8*)(rp + ((unsigned)(g * 16) ^ swz));
            short8 a2 = *(const short8*)(rp + ((unsigned)(64 + g * 16) ^ swz));

            f32x4 acc[4];
            #pragma unroll
            for (int j = 0; j < 4; ++j) {
                f32x4 a = {bias[j], bias[j], bias[j], bias[j]};
                a = __builtin_amdgcn_mfma_f32_16x16x32_bf16(a1, bf1[j], a, 0, 0, 0);
                a = __builtin_amdgcn_mfma_f32_16x16x32_bf16(a2, bf2[j], a, 0, 0, 0);
                acc[j] = a;
            }

            __syncthreads();   // WAR: previous tile's stg reads complete
            #pragma unroll
            for (int j = 0; j < 4; ++j) {
                const int c = colbase + j * 16;
                #pragma unroll
                for (int i = 0; i < 4; ++i)
                    stg[(g * 4 + i) * STG_STRIDE + c] = acc[j][i];
            }
            __syncthreads();   // RAW: staging visible to all

            // each wave stores 4 full 1KB rows, coalesced dwordx4
            #pragma unroll
            for (int q = 0; q < 4; ++q) {
                const int lrow = wv * 4 + q;
                const unsigned rid = rowid[rb + lrow];
                f32x4 v = *(const f32x4*)&stg[lrow * STG_STRIDE + 4 * lane];
                v[0] = mq[0] ? v[0] : NEG;
                v[1] = mq[1] ? v[1] : NEG;
                v[2] = mq[2] ? v[2] : NEG;
                v[3] = mq[3] ? v[3] : NEG;
                if (rid != 0xFFFFu)
                    __builtin_nontemporal_store(v,
                        (f32x4*)(outb + (size_t)rid * ACOL + 4 * lane));
            }
        }
    }
}

extern "C" void kernel_launch(void* const* d_in, const int* in_sizes, int n_in,
                              void* d_out, int out_size, void* d_ws, size_t ws_size,
                              hipStream_t stream) {
    const float* states    = (const float*)d_in[0];
    const int*   epoch_idx = (const int*)  d_in[1];
    const float* W1        = (const float*)d_in[2];
    const float* b1        = (const float*)d_in[3];
    const float* Wout      = (const float*)d_in[4];
    const float* bout      = (const float*)d_in[5];
    const int*   mask      = (const int*)  d_in[6];
    float*       out       = (float*)d_out;

    const int nB   = in_sizes[0] / SDIM;
    const int grid = (nB + SPB - 1) / SPB;
    actor_kernel<<<grid, 256, 0, stream>>>(states, epoch_idx, W1, b1,
                                           Wout, bout, mask, out, nB);
}